// Round 1
// baseline (722.820 us; speedup 1.0000x reference)
//
#include <hip/hip_runtime.h>

#define D    64
#define DOUT 34

// ---------- degree / norm ----------
__global__ void k_init_deg(int* deg, int N) {
    int i = blockIdx.x * blockDim.x + threadIdx.x;
    if (i < N) deg[i] = 1;  // self-loop contributes 1
}

__global__ void k_degree(const int* __restrict__ ei, int* deg, int E) {
    int e = blockIdx.x * blockDim.x + threadIdx.x;
    if (e < E) atomicAdd(&deg[ei[E + e]], 1);  // dst row of edge_index
}

__global__ void k_dinv(const int* __restrict__ deg, float* dinv, int N) {
    int i = blockIdx.x * blockDim.x + threadIdx.x;
    if (i < N) dinv[i] = rsqrtf((float)deg[i]);
}

// ---------- GEMM1: xw = x @ W1   [N,64] x [64,64] ----------
__global__ void k_gemm1(const float* __restrict__ x, const float* __restrict__ W,
                        float* __restrict__ xw, int N) {
    __shared__ float Ws[D * D];
    __shared__ float xs[4 * D];
    for (int i = threadIdx.x; i < D * D; i += 256) Ws[i] = W[i];
    int c  = threadIdx.x & 63;
    int rl = threadIdx.x >> 6;     // 0..3 (wave id)
    int r0 = blockIdx.x * 4;
    int r  = r0 + rl;
    __syncthreads();
    if (r < N) xs[threadIdx.x] = x[(size_t)r0 * D + threadIdx.x];
    __syncthreads();
    if (r < N) {
        float acc = 0.f;
#pragma unroll
        for (int k = 0; k < D; ++k) acc = fmaf(xs[rl * D + k], Ws[k * D + c], acc);
        xw[(size_t)r * D + c] = acc;
    }
}

// ---------- edge scatter layer 1: agg[dst] += xw[src] * norm ----------
__global__ void k_scatter1(const int* __restrict__ ei, const float* __restrict__ xw,
                           const float* __restrict__ dinv, float* agg, int E) {
    int w    = (blockIdx.x * blockDim.x + threadIdx.x) >> 6;  // edge id (1 wave/edge)
    int lane = threadIdx.x & 63;
    if (w >= E) return;
    int s = ei[w];
    int d = ei[E + w];
    float sc = dinv[s] * dinv[d];
    atomicAdd(&agg[(size_t)d * D + lane], xw[(size_t)s * D + lane] * sc);
}

// ---------- fused self-loop + bias + relu + row softmax (in place on agg) ----------
__global__ void k_softmax(float* agg, const float* __restrict__ xw,
                          const float* __restrict__ dinv, const float* __restrict__ b1,
                          int N) {
    int lane = threadIdx.x & 63;
    int r    = blockIdx.x * 4 + (threadIdx.x >> 6);
    if (r >= N) return;
    float di = dinv[r];
    float v  = agg[(size_t)r * D + lane] + xw[(size_t)r * D + lane] * di * di + b1[lane];
    v = fmaxf(v, 0.f);
    float m = v;
#pragma unroll
    for (int o = 32; o >= 1; o >>= 1) m = fmaxf(m, __shfl_xor(m, o));
    float e = __expf(v - m);
    float s = e;
#pragma unroll
    for (int o = 32; o >= 1; o >>= 1) s += __shfl_xor(s, o);
    agg[(size_t)r * D + lane] = e / s;
}

// ---------- GEMM2: xw2 = h @ W2   [N,64] x [64,34], compact stride-34 output ----------
__global__ void k_gemm2(const float* __restrict__ h, const float* __restrict__ W,
                        float* __restrict__ xw, int N) {
    __shared__ float Ws[D * DOUT];
    __shared__ float xs[4 * D];
    for (int i = threadIdx.x; i < D * DOUT; i += 256) Ws[i] = W[i];
    int c  = threadIdx.x & 63;
    int rl = threadIdx.x >> 6;
    int r0 = blockIdx.x * 4;
    int r  = r0 + rl;
    __syncthreads();
    if (r < N) xs[threadIdx.x] = h[(size_t)r0 * D + threadIdx.x];
    __syncthreads();
    if (r < N && c < DOUT) {
        float acc = 0.f;
#pragma unroll
        for (int k = 0; k < D; ++k) acc = fmaf(xs[rl * D + k], Ws[k * DOUT + c], acc);
        xw[(size_t)r * DOUT + c] = acc;
    }
}

// ---------- init out with bias + self-loop contribution ----------
__global__ void k_init_out(float* out, const float* __restrict__ xw2,
                           const float* __restrict__ dinv, const float* __restrict__ b2,
                           int N) {
    int i = blockIdx.x * blockDim.x + threadIdx.x;
    if (i >= N * DOUT) return;
    int r = i / DOUT;
    int c = i - r * DOUT;
    float di = dinv[r];
    out[i] = b2[c] + xw2[i] * di * di;
}

// ---------- edge scatter layer 2: out[dst] += xw2[src] * norm ----------
__global__ void k_scatter2(const int* __restrict__ ei, const float* __restrict__ xw,
                           const float* __restrict__ dinv, float* out, int E) {
    int w    = (blockIdx.x * blockDim.x + threadIdx.x) >> 6;
    int lane = threadIdx.x & 63;
    if (w >= E) return;
    if (lane >= DOUT) return;
    int s = ei[w];
    int d = ei[E + w];
    float sc = dinv[s] * dinv[d];
    atomicAdd(&out[(size_t)d * DOUT + lane], xw[(size_t)s * DOUT + lane] * sc);
}

extern "C" void kernel_launch(void* const* d_in, const int* in_sizes, int n_in,
                              void* d_out, int out_size, void* d_ws, size_t ws_size,
                              hipStream_t stream) {
    const float* x  = (const float*)d_in[0];
    const int*   ei = (const int*)d_in[1];
    const float* W1 = (const float*)d_in[2];
    const float* b1 = (const float*)d_in[3];
    const float* W2 = (const float*)d_in[4];
    const float* b2 = (const float*)d_in[5];
    float* out = (float*)d_out;

    const int N = in_sizes[0] / D;   // 100000
    const int E = in_sizes[1] / 2;   // 1200000

    // workspace layout (bytes): deg[N] | dinv[N] | xw1[N*64] (reused as xw2) | agg[N*64]
    char*  ws   = (char*)d_ws;
    int*   deg  = (int*)ws;
    float* dinv = (float*)(ws + (size_t)N * 4);
    float* xw1  = (float*)(ws + (size_t)N * 8);
    float* agg  = (float*)(ws + (size_t)N * 8 + (size_t)N * D * 4);
    float* xw2  = xw1;  // xw1 dead after k_softmax

    hipMemsetAsync(agg, 0, (size_t)N * D * 4, stream);

    k_init_deg<<<(N + 255) / 256, 256, 0, stream>>>(deg, N);
    k_degree  <<<(E + 255) / 256, 256, 0, stream>>>(ei, deg, E);
    k_dinv    <<<(N + 255) / 256, 256, 0, stream>>>(deg, dinv, N);

    k_gemm1   <<<(N + 3) / 4, 256, 0, stream>>>(x, W1, xw1, N);
    k_scatter1<<<(E + 3) / 4, 256, 0, stream>>>(ei, xw1, dinv, agg, E);
    k_softmax <<<(N + 3) / 4, 256, 0, stream>>>(agg, xw1, dinv, b1, N);

    k_gemm2   <<<(N + 3) / 4, 256, 0, stream>>>(agg, W2, xw2, N);
    k_init_out<<<(N * DOUT + 255) / 256, 256, 0, stream>>>(out, xw2, dinv, b2, N);
    k_scatter2<<<(E + 3) / 4, 256, 0, stream>>>(ei, xw2, dinv, out, E);
}

// Round 2
// 460.307 us; speedup vs baseline: 1.5703x; 1.5703x over previous
//
#include <hip/hip_runtime.h>

#define D    64
#define DOUT 34

// ---------- count incoming edges per node ----------
__global__ void k_count(const int* __restrict__ ei, int* cnt, int E) {
    int e = blockIdx.x * blockDim.x + threadIdx.x;
    if (e < E) atomicAdd(&cnt[ei[E + e]], 1);  // dst row
}

// ---------- block-scan offsets (atomic base), plus fill=0 and dinv ----------
__global__ void k_offsets(const int* __restrict__ cnt, int* off, int* fill,
                          float* dinv, int* gcount, int N) {
    __shared__ int s[256];
    int i = blockIdx.x * 256 + threadIdx.x;
    int c = (i < N) ? cnt[i] : 0;
    s[threadIdx.x] = c;
    __syncthreads();
#pragma unroll
    for (int d = 1; d < 256; d <<= 1) {
        int v = (threadIdx.x >= d) ? s[threadIdx.x - d] : 0;
        __syncthreads();
        s[threadIdx.x] += v;
        __syncthreads();
    }
    __shared__ int base;
    if (threadIdx.x == 255) base = atomicAdd(gcount, s[255]);
    __syncthreads();
    if (i < N) {
        off[i]  = base + s[threadIdx.x] - c;   // exclusive prefix within valid slice
        fill[i] = 0;
        dinv[i] = rsqrtf((float)(c + 1));      // +1 self-loop
    }
}

// ---------- place edges into CSR slots ----------
__global__ void k_place(const int* __restrict__ ei, const int* __restrict__ off,
                        int* fill, int* csr, int E) {
    int e = blockIdx.x * blockDim.x + threadIdx.x;
    if (e >= E) return;
    int d   = ei[E + e];
    int pos = off[d] + atomicAdd(&fill[d], 1);
    csr[pos] = ei[e];  // src
}

// ---------- GEMM1: xw1 = x @ W1   [N,64] x [64,64] ----------
__global__ void k_gemm1(const float* __restrict__ x, const float* __restrict__ W,
                        float* __restrict__ xw, int N) {
    __shared__ float Ws[D * D];
    __shared__ float xs[4 * D];
    for (int i = threadIdx.x; i < D * D; i += 256) Ws[i] = W[i];
    int c  = threadIdx.x & 63;
    int rl = threadIdx.x >> 6;
    int r0 = blockIdx.x * 4;
    int r  = r0 + rl;
    __syncthreads();
    if (r < N) xs[threadIdx.x] = x[(size_t)r0 * D + threadIdx.x];
    __syncthreads();
    if (r < N) {
        float acc = 0.f;
#pragma unroll
        for (int k = 0; k < D; ++k) acc = fmaf(xs[rl * D + k], Ws[k * D + c], acc);
        xw[(size_t)r * D + c] = acc;
    }
}

// ---------- gather layer1 + selfloop + bias + relu + softmax + h@W2 fused ----------
// one wave per node; N must be multiple of 4 (100000 is)
__global__ void k_gather1(const int* __restrict__ off, const int* __restrict__ cnt,
                          const int* __restrict__ csr, const float* __restrict__ xw1,
                          const float* __restrict__ dinv, const float* __restrict__ b1,
                          const float* __restrict__ W2, float* __restrict__ xw2, int N) {
    __shared__ float W2s[D * DOUT];
    __shared__ float hs[4][D];
    for (int i = threadIdx.x; i < D * DOUT; i += 256) W2s[i] = W2[i];
    int lane = threadIdx.x & 63;
    int w    = threadIdx.x >> 6;
    int r    = blockIdx.x * 4 + w;
    float di  = dinv[r];
    float acc = fmaf(xw1[(size_t)r * D + lane], di * di, b1[lane]);  // self-loop + bias
    int e  = off[r];
    int e1 = e + cnt[r];
    for (; e + 1 < e1; e += 2) {  // 2x unroll: independent loads
        int s0 = csr[e], s1 = csr[e + 1];
        float n0 = dinv[s0] * di, n1 = dinv[s1] * di;
        float v0 = xw1[(size_t)s0 * D + lane];
        float v1 = xw1[(size_t)s1 * D + lane];
        acc = fmaf(v0, n0, acc);
        acc = fmaf(v1, n1, acc);
    }
    if (e < e1) {
        int s0 = csr[e];
        acc = fmaf(xw1[(size_t)s0 * D + lane], dinv[s0] * di, acc);
    }
    // relu + softmax across the 64 lanes
    float v = fmaxf(acc, 0.f);
    float m = v;
#pragma unroll
    for (int o = 32; o >= 1; o >>= 1) m = fmaxf(m, __shfl_xor(m, o));
    float ex = __expf(v - m);
    float sm = ex;
#pragma unroll
    for (int o = 32; o >= 1; o >>= 1) sm += __shfl_xor(sm, o);
    float h = ex / sm;
    hs[w][lane] = h;
    __syncthreads();
    // xw2 row = h @ W2  (lanes 0..33)
    if (lane < DOUT) {
        float a2 = 0.f;
#pragma unroll
        for (int k = 0; k < D; ++k) a2 = fmaf(hs[w][k], W2s[k * DOUT + lane], a2);
        xw2[(size_t)r * DOUT + lane] = a2;
    }
}

// ---------- gather layer2 + selfloop + bias ----------
__global__ void k_gather2(const int* __restrict__ off, const int* __restrict__ cnt,
                          const int* __restrict__ csr, const float* __restrict__ xw2,
                          const float* __restrict__ dinv, const float* __restrict__ b2,
                          float* __restrict__ out, int N) {
    int lane = threadIdx.x & 63;
    int r    = blockIdx.x * 4 + (threadIdx.x >> 6);
    if (r >= N || lane >= DOUT) return;
    float di  = dinv[r];
    float acc = fmaf(xw2[(size_t)r * DOUT + lane], di * di, b2[lane]);
    int e  = off[r];
    int e1 = e + cnt[r];
    for (; e + 1 < e1; e += 2) {
        int s0 = csr[e], s1 = csr[e + 1];
        float n0 = dinv[s0] * di, n1 = dinv[s1] * di;
        float v0 = xw2[(size_t)s0 * DOUT + lane];
        float v1 = xw2[(size_t)s1 * DOUT + lane];
        acc = fmaf(v0, n0, acc);
        acc = fmaf(v1, n1, acc);
    }
    if (e < e1) {
        int s0 = csr[e];
        acc = fmaf(xw2[(size_t)s0 * DOUT + lane], dinv[s0] * di, acc);
    }
    out[(size_t)r * DOUT + lane] = acc;
}

extern "C" void kernel_launch(void* const* d_in, const int* in_sizes, int n_in,
                              void* d_out, int out_size, void* d_ws, size_t ws_size,
                              hipStream_t stream) {
    const float* x  = (const float*)d_in[0];
    const int*   ei = (const int*)d_in[1];
    const float* W1 = (const float*)d_in[2];
    const float* b1 = (const float*)d_in[3];
    const float* W2 = (const float*)d_in[4];
    const float* b2 = (const float*)d_in[5];
    float* out = (float*)d_out;

    const int N = in_sizes[0] / D;   // 100000
    const int E = in_sizes[1] / 2;   // 1200000

    // ws layout: gcount[1] | cnt[N] | off[N] | fill[N] | dinv[N] | csr[E] | xw1[N*64] | xw2[N*34]
    char*  ws     = (char*)d_ws;
    int*   gcount = (int*)ws;
    int*   cnt    = (int*)(ws + 4);
    int*   off    = (int*)(ws + 4 + (size_t)N * 4);
    int*   fill   = (int*)(ws + 4 + (size_t)N * 8);
    float* dinv   = (float*)(ws + 4 + (size_t)N * 12);
    int*   csr    = (int*)(ws + 4 + (size_t)N * 16);
    float* xw1    = (float*)(ws + 4 + (size_t)N * 16 + (size_t)E * 4);
    float* xw2    = (float*)(ws + 4 + (size_t)N * 16 + (size_t)E * 4 + (size_t)N * D * 4);

    hipMemsetAsync(gcount, 0, 4 + (size_t)N * 4, stream);  // gcount + cnt

    k_count  <<<(E + 255) / 256, 256, 0, stream>>>(ei, cnt, E);
    k_offsets<<<(N + 255) / 256, 256, 0, stream>>>(cnt, off, fill, dinv, gcount, N);
    k_place  <<<(E + 255) / 256, 256, 0, stream>>>(ei, off, fill, csr, E);

    k_gemm1  <<<(N + 3) / 4, 256, 0, stream>>>(x, W1, xw1, N);
    k_gather1<<<N / 4, 256, 0, stream>>>(off, cnt, csr, xw1, dinv, b1, W2, xw2, N);
    k_gather2<<<(N + 3) / 4, 256, 0, stream>>>(off, cnt, csr, xw2, dinv, b2, out, N);
}

// Round 3
// 394.112 us; speedup vs baseline: 1.8340x; 1.1680x over previous
//
#include <hip/hip_runtime.h>

#define D    64
#define DOUT 34
#define S2   36   // padded stride for layer-2 feature rows (16B-aligned: 36*4=144)

// ---------- count incoming edges per node ----------
__global__ void k_count(const int* __restrict__ ei, int* cnt, int E) {
    int e = blockIdx.x * blockDim.x + threadIdx.x;
    if (e < E) atomicAdd(&cnt[ei[E + e]], 1);  // dst row
}

// ---------- block-scan offsets (atomic base) + dinv ----------
__global__ void k_offsets(const int* __restrict__ cnt, int* off,
                          float* dinv, int* gcount, int N) {
    __shared__ int s[256];
    int i = blockIdx.x * 256 + threadIdx.x;
    int c = (i < N) ? cnt[i] : 0;
    s[threadIdx.x] = c;
    __syncthreads();
#pragma unroll
    for (int d = 1; d < 256; d <<= 1) {
        int v = (threadIdx.x >= d) ? s[threadIdx.x - d] : 0;
        __syncthreads();
        s[threadIdx.x] += v;
        __syncthreads();
    }
    __shared__ int base;
    if (threadIdx.x == 255) base = atomicAdd(gcount, s[255]);
    __syncthreads();
    if (i < N) {
        off[i]  = base + s[threadIdx.x] - c;
        dinv[i] = rsqrtf((float)(c + 1));  // +1 self-loop
    }
}

// ---------- place edges: csr2[pos] = {src, norm}; off becomes end-pointer ----------
__global__ void k_place(const int* __restrict__ ei, int* off,
                        const float* __restrict__ dinv, int2* csr2, int E) {
    int e = blockIdx.x * blockDim.x + threadIdx.x;
    if (e >= E) return;
    int s = ei[e];
    int d = ei[E + e];
    int pos = atomicAdd(&off[d], 1);
    csr2[pos] = make_int2(s, __float_as_int(dinv[s] * dinv[d]));
}

// ---------- GEMM1: xw1 = x @ W1, 16 rows/block ----------
__global__ void k_gemm1(const float* __restrict__ x, const float* __restrict__ W,
                        float* __restrict__ xw, int N) {
    __shared__ float Ws[D * D];
    __shared__ float xs[16 * D];
    const float4* W4 = (const float4*)W;
    float4* Ws4 = (float4*)Ws;
    for (int i = threadIdx.x; i < D * D / 4; i += 256) Ws4[i] = W4[i];
    size_t r0 = (size_t)blockIdx.x * 16;
    const float4* x4 = (const float4*)(x + r0 * D);
    float4* xs4 = (float4*)xs;
    for (int i = threadIdx.x; i < 16 * D / 4; i += 256) xs4[i] = x4[i];
    __syncthreads();
    int c  = threadIdx.x & 63;
    int rg = threadIdx.x >> 6;
#pragma unroll
    for (int rr = 0; rr < 4; ++rr) {
        int rl = rg * 4 + rr;
        float acc = 0.f;
#pragma unroll
        for (int k = 0; k < D; ++k) acc = fmaf(xs[rl * D + k], Ws[k * D + c], acc);
        xw[(r0 + rl) * D + c] = acc;
    }
}

// ---------- gather1 + selfloop + bias + relu + softmax + h@W2, quarter-wave float4 ----------
__global__ void k_gather1(const int* __restrict__ off, const int* __restrict__ cnt,
                          const int2* __restrict__ csr2, const float* __restrict__ xw1,
                          const float* __restrict__ dinv, const float* __restrict__ b1,
                          const float* __restrict__ W2, float* __restrict__ xw2, int N) {
    __shared__ float W2s[D * DOUT];
    __shared__ float hs[4][D];
    for (int i = threadIdx.x; i < D * DOUT; i += 256) W2s[i] = W2[i];
    int lane = threadIdx.x & 63;
    int w    = threadIdx.x >> 6;
    int q    = lane >> 4;
    int ql   = lane & 15;
    int r    = blockIdx.x * 4 + w;
    if (r >= N) r = N - 1;  // duplicate work, benign
    float di = dinv[r];
    int e1 = off[r];
    int n  = cnt[r];
    int e0 = e1 - n;
    float4 acc = make_float4(0.f, 0.f, 0.f, 0.f);
    int i = q;
    for (; i + 4 < n; i += 8) {
        int2 p0 = csr2[e0 + i];
        int2 p1 = csr2[e0 + i + 4];
        float c0 = __int_as_float(p0.y);
        float c1 = __int_as_float(p1.y);
        float4 v0 = ((const float4*)(xw1 + (size_t)p0.x * D))[ql];
        float4 v1 = ((const float4*)(xw1 + (size_t)p1.x * D))[ql];
        acc.x = fmaf(v0.x, c0, acc.x); acc.y = fmaf(v0.y, c0, acc.y);
        acc.z = fmaf(v0.z, c0, acc.z); acc.w = fmaf(v0.w, c0, acc.w);
        acc.x = fmaf(v1.x, c1, acc.x); acc.y = fmaf(v1.y, c1, acc.y);
        acc.z = fmaf(v1.z, c1, acc.z); acc.w = fmaf(v1.w, c1, acc.w);
    }
    if (i < n) {
        int2 p0 = csr2[e0 + i];
        float c0 = __int_as_float(p0.y);
        float4 v0 = ((const float4*)(xw1 + (size_t)p0.x * D))[ql];
        acc.x = fmaf(v0.x, c0, acc.x); acc.y = fmaf(v0.y, c0, acc.y);
        acc.z = fmaf(v0.z, c0, acc.z); acc.w = fmaf(v0.w, c0, acc.w);
    }
    // combine quarters (each quarter's lane ql holds the same feature slice)
    acc.x += __shfl_xor(acc.x, 16); acc.y += __shfl_xor(acc.y, 16);
    acc.z += __shfl_xor(acc.z, 16); acc.w += __shfl_xor(acc.w, 16);
    acc.x += __shfl_xor(acc.x, 32); acc.y += __shfl_xor(acc.y, 32);
    acc.z += __shfl_xor(acc.z, 32); acc.w += __shfl_xor(acc.w, 32);
    // self-loop + bias
    float4 xr = ((const float4*)(xw1 + (size_t)r * D))[ql];
    float4 bb = ((const float4*)b1)[ql];
    float dii = di * di;
    float4 v;
    v.x = fmaf(xr.x, dii, acc.x) + bb.x;
    v.y = fmaf(xr.y, dii, acc.y) + bb.y;
    v.z = fmaf(xr.z, dii, acc.z) + bb.z;
    v.w = fmaf(xr.w, dii, acc.w) + bb.w;
    // relu
    v.x = fmaxf(v.x, 0.f); v.y = fmaxf(v.y, 0.f);
    v.z = fmaxf(v.z, 0.f); v.w = fmaxf(v.w, 0.f);
    // softmax over 64 features (distributed over 16 lanes, replicated in quarters)
    float m = fmaxf(fmaxf(v.x, v.y), fmaxf(v.z, v.w));
#pragma unroll
    for (int o = 8; o >= 1; o >>= 1) m = fmaxf(m, __shfl_xor(m, o));
    float4 ex;
    ex.x = __expf(v.x - m); ex.y = __expf(v.y - m);
    ex.z = __expf(v.z - m); ex.w = __expf(v.w - m);
    float s = ex.x + ex.y + ex.z + ex.w;
#pragma unroll
    for (int o = 8; o >= 1; o >>= 1) s += __shfl_xor(s, o);
    float inv = 1.f / s;
    float4 h = make_float4(ex.x * inv, ex.y * inv, ex.z * inv, ex.w * inv);
    if (q == 0) ((float4*)hs[w])[ql] = h;
    __syncthreads();
    // xw2 row = h @ W2 (padded stride 36, lanes 34..35 zero)
    if (lane < DOUT) {
        float a2 = 0.f;
#pragma unroll
        for (int k = 0; k < D; ++k) a2 = fmaf(hs[w][k], W2s[k * DOUT + lane], a2);
        xw2[(size_t)r * S2 + lane] = a2;
    } else if (lane < S2) {
        xw2[(size_t)r * S2 + lane] = 0.f;
    }
}

// ---------- gather2 + selfloop + bias, quarter-wave float4 over padded rows ----------
__global__ void k_gather2(const int* __restrict__ off, const int* __restrict__ cnt,
                          const int2* __restrict__ csr2, const float* __restrict__ xw2,
                          const float* __restrict__ dinv, const float* __restrict__ b2,
                          float* __restrict__ out, int N) {
    int lane = threadIdx.x & 63;
    int w    = threadIdx.x >> 6;
    int q    = lane >> 4;
    int ql   = lane & 15;
    int r    = blockIdx.x * 4 + w;
    if (r >= N) r = N - 1;
    bool act = (ql < 9);  // 9 float4 = 36 floats per row
    float di = dinv[r];
    int e1 = off[r];
    int n  = cnt[r];
    int e0 = e1 - n;
    float4 acc = make_float4(0.f, 0.f, 0.f, 0.f);
    int i = q;
    for (; i + 4 < n; i += 8) {
        int2 p0 = csr2[e0 + i];
        int2 p1 = csr2[e0 + i + 4];
        float c0 = __int_as_float(p0.y);
        float c1 = __int_as_float(p1.y);
        if (act) {
            float4 v0 = ((const float4*)(xw2 + (size_t)p0.x * S2))[ql];
            float4 v1 = ((const float4*)(xw2 + (size_t)p1.x * S2))[ql];
            acc.x = fmaf(v0.x, c0, acc.x); acc.y = fmaf(v0.y, c0, acc.y);
            acc.z = fmaf(v0.z, c0, acc.z); acc.w = fmaf(v0.w, c0, acc.w);
            acc.x = fmaf(v1.x, c1, acc.x); acc.y = fmaf(v1.y, c1, acc.y);
            acc.z = fmaf(v1.z, c1, acc.z); acc.w = fmaf(v1.w, c1, acc.w);
        }
    }
    if (i < n) {
        int2 p0 = csr2[e0 + i];
        float c0 = __int_as_float(p0.y);
        if (act) {
            float4 v0 = ((const float4*)(xw2 + (size_t)p0.x * S2))[ql];
            acc.x = fmaf(v0.x, c0, acc.x); acc.y = fmaf(v0.y, c0, acc.y);
            acc.z = fmaf(v0.z, c0, acc.z); acc.w = fmaf(v0.w, c0, acc.w);
        }
    }
    acc.x += __shfl_xor(acc.x, 16); acc.y += __shfl_xor(acc.y, 16);
    acc.z += __shfl_xor(acc.z, 16); acc.w += __shfl_xor(acc.w, 16);
    acc.x += __shfl_xor(acc.x, 32); acc.y += __shfl_xor(acc.y, 32);
    acc.z += __shfl_xor(acc.z, 32); acc.w += __shfl_xor(acc.w, 32);
    if (q == 0 && act) {
        float4 xr = ((const float4*)(xw2 + (size_t)r * S2))[ql];
        float dii = di * di;
        float vals[4];
        vals[0] = fmaf(xr.x, dii, acc.x);
        vals[1] = fmaf(xr.y, dii, acc.y);
        vals[2] = fmaf(xr.z, dii, acc.z);
        vals[3] = fmaf(xr.w, dii, acc.w);
        int f = 4 * ql;
#pragma unroll
        for (int c = 0; c < 4; ++c)
            if (f + c < DOUT) out[(size_t)r * DOUT + f + c] = vals[c] + b2[f + c];
    }
}

extern "C" void kernel_launch(void* const* d_in, const int* in_sizes, int n_in,
                              void* d_out, int out_size, void* d_ws, size_t ws_size,
                              hipStream_t stream) {
    const float* x  = (const float*)d_in[0];
    const int*   ei = (const int*)d_in[1];
    const float* W1 = (const float*)d_in[2];
    const float* b1 = (const float*)d_in[3];
    const float* W2 = (const float*)d_in[4];
    const float* b2 = (const float*)d_in[5];
    float* out = (float*)d_out;

    const int N = in_sizes[0] / D;   // 100000
    const int E = in_sizes[1] / 2;   // 1200000

    // ws: gcount(16B pad) | cnt[N] | off[N] | dinv[N] | csr2[E]{int2} | xw1[N*64] | xw2[N*36]
    char*  ws     = (char*)d_ws;
    int*   gcount = (int*)ws;
    int*   cnt    = (int*)(ws + 16);
    int*   off    = (int*)(ws + 16 + (size_t)N * 4);
    float* dinv   = (float*)(ws + 16 + (size_t)N * 8);
    int2*  csr2   = (int2*)(ws + 16 + (size_t)N * 12);
    float* xw1    = (float*)(ws + 16 + (size_t)N * 12 + (size_t)E * 8);
    float* xw2    = (float*)(ws + 16 + (size_t)N * 12 + (size_t)E * 8 + (size_t)N * D * 4);

    hipMemsetAsync(ws, 0, 16 + (size_t)N * 4, stream);  // gcount + cnt

    k_count  <<<(E + 255) / 256, 256, 0, stream>>>(ei, cnt, E);
    k_offsets<<<(N + 255) / 256, 256, 0, stream>>>(cnt, off, dinv, gcount, N);
    k_place  <<<(E + 255) / 256, 256, 0, stream>>>(ei, off, dinv, csr2, E);

    k_gemm1  <<<(N + 15) / 16, 256, 0, stream>>>(x, W1, xw1, N);
    k_gather1<<<(N + 3) / 4, 256, 0, stream>>>(off, cnt, csr2, xw1, dinv, b1, W2, xw2, N);
    k_gather2<<<(N + 3) / 4, 256, 0, stream>>>(off, cnt, csr2, xw2, dinv, b2, out, N);
}

// Round 5
// 370.277 us; speedup vs baseline: 1.9521x; 1.0644x over previous
//
#include <hip/hip_runtime.h>
#include <hip/hip_fp16.h>

#define D    64
#define DOUT 34
#define S2H  40   // layer-2 row stride in halves (80 B, 8B-aligned)

// ---------- count incoming edges per node ----------
__global__ void k_count(const int* __restrict__ ei, int* cnt, int E) {
    int e = blockIdx.x * blockDim.x + threadIdx.x;
    if (e < E) atomicAdd(&cnt[ei[E + e]], 1);  // dst row
}

// ---------- block-scan offsets (atomic base) + dinv ----------
__global__ void k_offsets(const int* __restrict__ cnt, int* off,
                          float* dinv, int* gcount, int N) {
    __shared__ int s[256];
    int i = blockIdx.x * 256 + threadIdx.x;
    int c = (i < N) ? cnt[i] : 0;
    s[threadIdx.x] = c;
    __syncthreads();
#pragma unroll
    for (int d = 1; d < 256; d <<= 1) {
        int v = (threadIdx.x >= d) ? s[threadIdx.x - d] : 0;
        __syncthreads();
        s[threadIdx.x] += v;
        __syncthreads();
    }
    __shared__ int base;
    if (threadIdx.x == 255) base = atomicAdd(gcount, s[255]);
    __syncthreads();
    if (i < N) {
        off[i]  = base + s[threadIdx.x] - c;
        dinv[i] = rsqrtf((float)(c + 1));  // +1 self-loop
    }
}

// ---------- place edges: csr2[pos] = {src, norm}; off becomes end-pointer ----------
__global__ void k_place(const int* __restrict__ ei, int* off,
                        const float* __restrict__ dinv, int2* csr2, int E) {
    int e = blockIdx.x * blockDim.x + threadIdx.x;
    if (e >= E) return;
    int s = ei[e];
    int d = ei[E + e];
    int pos = atomicAdd(&off[d], 1);
    csr2[pos] = make_int2(s, __float_as_int(dinv[s] * dinv[d]));
}

// ---------- GEMM1: xw1h = fp16(x @ W1), 16 rows/block ----------
__global__ void k_gemm1(const float* __restrict__ x, const float* __restrict__ W,
                        __half* __restrict__ xwh, int N) {
    __shared__ float Ws[D * D];
    __shared__ float xs[16 * D];
    const float4* W4 = (const float4*)W;
    float4* Ws4 = (float4*)Ws;
    for (int i = threadIdx.x; i < D * D / 4; i += 256) Ws4[i] = W4[i];
    size_t r0 = (size_t)blockIdx.x * 16;
    const float4* x4 = (const float4*)(x + r0 * D);
    float4* xs4 = (float4*)xs;
    for (int i = threadIdx.x; i < 16 * D / 4; i += 256) xs4[i] = x4[i];
    __syncthreads();
    int c  = threadIdx.x & 63;
    int rg = threadIdx.x >> 6;
#pragma unroll
    for (int rr = 0; rr < 4; ++rr) {
        int rl = rg * 4 + rr;
        float acc = 0.f;
#pragma unroll
        for (int k = 0; k < D; ++k) acc = fmaf(xs[rl * D + k], Ws[k * D + c], acc);
        xwh[(r0 + rl) * D + c] = __float2half(acc);
    }
}

__device__ __forceinline__ void fma8(float* a, float4 raw, float c) {
    __half2* hp = (__half2*)&raw;
#pragma unroll
    for (int k = 0; k < 4; ++k) {
        float2 f = __half22float2(hp[k]);
        a[2 * k]     = fmaf(f.x, c, a[2 * k]);
        a[2 * k + 1] = fmaf(f.y, c, a[2 * k + 1]);
    }
}

// ---------- gather1 + selfloop + bias + relu + softmax + h@W2 fused ----------
// one wave per node, eighth-wave (8 lanes x 16B) row gather.
// csr prefetch + shuffle; inner loop is WAVE-UNIFORM (branch-free): shuffles
// always execute with all 64 lanes active, tail handled by weight=0 selects.
__global__ void k_gather1(const int* __restrict__ off, const int* __restrict__ cnt,
                          const int2* __restrict__ csr2, const __half* __restrict__ xw1h,
                          const float* __restrict__ dinv, const float* __restrict__ b1,
                          const float* __restrict__ W2, __half* __restrict__ xw2h, int N) {
    __shared__ float W2s[D * DOUT];
    __shared__ float hs[4][D];
    for (int i = threadIdx.x; i < D * DOUT; i += 256) W2s[i] = W2[i];
    int lane = threadIdx.x & 63;
    int w    = threadIdx.x >> 6;
    int g    = lane >> 3;   // edge slot within iteration (0..7)
    int gl   = lane & 7;    // 16B chunk within row (0..7)
    int r    = blockIdx.x * 4 + w;   // N % 4 == 0
    float di = dinv[r];
    int e1 = off[r];
    int n  = cnt[r];
    int e0 = e1 - n;
    float acc[8] = {0.f, 0.f, 0.f, 0.f, 0.f, 0.f, 0.f, 0.f};
    for (int base = 0; base < n; base += 64) {
        int nb = n - base; if (nb > 64) nb = 64;   // wave-uniform
        int2 p = make_int2(0, 0);
        if (lane < nb) p = csr2[e0 + base + lane];
        int   px = p.x;
        float pc = __int_as_float(p.y);
        int nIter = (nb + 15) >> 4;                // wave-uniform trip count
        int idx = g;
        for (int t = 0; t < nIter; ++t, idx += 16) {
            bool a0 = (idx < nb);
            bool a1 = (idx + 8 < nb);
            int i0 = a0 ? idx : 0;
            int i1 = a1 ? (idx + 8) : 0;
            int   s0  = __shfl(px, i0);
            int   s1  = __shfl(px, i1);
            float c0r = __shfl(pc, i0);
            float c1r = __shfl(pc, i1);
            float c0 = a0 ? c0r : 0.f;
            float c1 = a1 ? c1r : 0.f;
            float4 r0 = ((const float4*)(xw1h + (size_t)s0 * D))[gl];
            float4 r1 = ((const float4*)(xw1h + (size_t)s1 * D))[gl];
            fma8(acc, r0, c0);
            fma8(acc, r1, c1);
        }
    }
    // combine the 8 edge-groups (butterfly over lane bits 3,4,5)
#pragma unroll
    for (int k = 0; k < 8; ++k) {
        acc[k] += __shfl_xor(acc[k], 8);
        acc[k] += __shfl_xor(acc[k], 16);
        acc[k] += __shfl_xor(acc[k], 32);
    }
    // self-loop + bias (replicated across groups)
    float4 sr = ((const float4*)(xw1h + (size_t)r * D))[gl];
    float dii = di * di;
    fma8(acc, sr, dii);
    float4 bb0 = ((const float4*)b1)[2 * gl];
    float4 bb1 = ((const float4*)b1)[2 * gl + 1];
    acc[0] += bb0.x; acc[1] += bb0.y; acc[2] += bb0.z; acc[3] += bb0.w;
    acc[4] += bb1.x; acc[5] += bb1.y; acc[6] += bb1.z; acc[7] += bb1.w;
    // relu + softmax over 64 features (8 per lane, butterfly over lane bits 0..2)
    float m = 0.f;
#pragma unroll
    for (int k = 0; k < 8; ++k) { acc[k] = fmaxf(acc[k], 0.f); m = fmaxf(m, acc[k]); }
#pragma unroll
    for (int o = 4; o >= 1; o >>= 1) m = fmaxf(m, __shfl_xor(m, o));
    float s = 0.f;
#pragma unroll
    for (int k = 0; k < 8; ++k) { acc[k] = __expf(acc[k] - m); s += acc[k]; }
#pragma unroll
    for (int o = 4; o >= 1; o >>= 1) s += __shfl_xor(s, o);
    float inv = 1.f / s;
    if (g == 0) {
#pragma unroll
        for (int k = 0; k < 8; ++k) hs[w][8 * gl + k] = acc[k] * inv;
    }
    __syncthreads();
    // xw2 row = h @ W2, fp16 out, stride 40 (feats 34..39 zero)
    if (lane < DOUT) {
        float a2 = 0.f;
#pragma unroll
        for (int k = 0; k < D; ++k) a2 = fmaf(hs[w][k], W2s[k * DOUT + lane], a2);
        xw2h[(size_t)r * S2H + lane] = __float2half(a2);
    } else if (lane < S2H) {
        xw2h[(size_t)r * S2H + lane] = __half(0.f);
    }
}

// ---------- gather2 + selfloop + bias, quarter-wave (10 lanes x 8B), uniform loop ----------
__global__ void k_gather2(const int* __restrict__ off, const int* __restrict__ cnt,
                          const int2* __restrict__ csr2, const __half* __restrict__ xw2h,
                          const float* __restrict__ dinv, const float* __restrict__ b2,
                          float* __restrict__ out, int N) {
    int lane = threadIdx.x & 63;
    int w    = threadIdx.x >> 6;
    int q    = lane >> 4;   // edge slot (0..3)
    int ql   = lane & 15;   // 8B chunk (0..9 active)
    int r    = blockIdx.x * 4 + w;
    bool act = (ql < 10);
    float di = dinv[r];
    int e1 = off[r];
    int n  = cnt[r];
    int e0 = e1 - n;
    float acc[4] = {0.f, 0.f, 0.f, 0.f};
    for (int base = 0; base < n; base += 64) {
        int nb = n - base; if (nb > 64) nb = 64;
        int2 p = make_int2(0, 0);
        if (lane < nb) p = csr2[e0 + base + lane];
        int   px = p.x;
        float pc = __int_as_float(p.y);
        int nIter = (nb + 7) >> 3;                 // wave-uniform
        int idx = q;
        for (int t = 0; t < nIter; ++t, idx += 8) {
            bool a0 = (idx < nb);
            bool a1 = (idx + 4 < nb);
            int i0 = a0 ? idx : 0;
            int i1 = a1 ? (idx + 4) : 0;
            int   s0  = __shfl(px, i0);
            int   s1  = __shfl(px, i1);
            float c0r = __shfl(pc, i0);
            float c1r = __shfl(pc, i1);
            float c0 = a0 ? c0r : 0.f;
            float c1 = a1 ? c1r : 0.f;
            if (act) {
                float2 r0 = ((const float2*)(xw2h + (size_t)s0 * S2H))[ql];
                float2 r1 = ((const float2*)(xw2h + (size_t)s1 * S2H))[ql];
                __half2* h0 = (__half2*)&r0;
                __half2* h1 = (__half2*)&r1;
                float2 f0 = __half22float2(h0[0]), f1 = __half22float2(h0[1]);
                acc[0] = fmaf(f0.x, c0, acc[0]); acc[1] = fmaf(f0.y, c0, acc[1]);
                acc[2] = fmaf(f1.x, c0, acc[2]); acc[3] = fmaf(f1.y, c0, acc[3]);
                float2 g0 = __half22float2(h1[0]), g1 = __half22float2(h1[1]);
                acc[0] = fmaf(g0.x, c1, acc[0]); acc[1] = fmaf(g0.y, c1, acc[1]);
                acc[2] = fmaf(g1.x, c1, acc[2]); acc[3] = fmaf(g1.y, c1, acc[3]);
            }
        }
    }
#pragma unroll
    for (int k = 0; k < 4; ++k) {
        acc[k] += __shfl_xor(acc[k], 16);
        acc[k] += __shfl_xor(acc[k], 32);
    }
    if (q == 0 && ql < 9) {  // features 4*ql .. 4*ql+3, guard < 34
        float2 sr = ((const float2*)(xw2h + (size_t)r * S2H))[ql];
        __half2* hp = (__half2*)&sr;
        float2 f0 = __half22float2(hp[0]), f1 = __half22float2(hp[1]);
        float dii = di * di;
        float vals[4];
        vals[0] = fmaf(f0.x, dii, acc[0]);
        vals[1] = fmaf(f0.y, dii, acc[1]);
        vals[2] = fmaf(f1.x, dii, acc[2]);
        vals[3] = fmaf(f1.y, dii, acc[3]);
        int f = 4 * ql;
#pragma unroll
        for (int c = 0; c < 4; ++c)
            if (f + c < DOUT) out[(size_t)r * DOUT + f + c] = vals[c] + b2[f + c];
    }
}

extern "C" void kernel_launch(void* const* d_in, const int* in_sizes, int n_in,
                              void* d_out, int out_size, void* d_ws, size_t ws_size,
                              hipStream_t stream) {
    const float* x  = (const float*)d_in[0];
    const int*   ei = (const int*)d_in[1];
    const float* W1 = (const float*)d_in[2];
    const float* b1 = (const float*)d_in[3];
    const float* W2 = (const float*)d_in[4];
    const float* b2 = (const float*)d_in[5];
    float* out = (float*)d_out;

    const int N = in_sizes[0] / D;   // 100000
    const int E = in_sizes[1] / 2;   // 1200000

    // ws: gcount(16B) | cnt[N] | off[N] | dinv[N] | csr2[E]{int2} | xw1h[N*64 fp16] | xw2h[N*40 fp16]
    char*   ws     = (char*)d_ws;
    int*    gcount = (int*)ws;
    int*    cnt    = (int*)(ws + 16);
    int*    off    = (int*)(ws + 16 + (size_t)N * 4);
    float*  dinv   = (float*)(ws + 16 + (size_t)N * 8);
    int2*   csr2   = (int2*)(ws + 16 + (size_t)N * 12);
    __half* xw1h   = (__half*)(ws + 16 + (size_t)N * 12 + (size_t)E * 8);
    __half* xw2h   = (__half*)(ws + 16 + (size_t)N * 12 + (size_t)E * 8 + (size_t)N * D * 2);

    hipMemsetAsync(ws, 0, 16 + (size_t)N * 4, stream);  // gcount + cnt

    k_count  <<<(E + 255) / 256, 256, 0, stream>>>(ei, cnt, E);
    k_offsets<<<(N + 255) / 256, 256, 0, stream>>>(cnt, off, dinv, gcount, N);
    k_place  <<<(E + 255) / 256, 256, 0, stream>>>(ei, off, dinv, csr2, E);

    k_gemm1  <<<(N + 15) / 16, 256, 0, stream>>>(x, W1, xw1h, N);
    k_gather1<<<N / 4, 256, 0, stream>>>(off, cnt, csr2, xw1h, dinv, b1, W2, xw2h, N);
    k_gather2<<<N / 4, 256, 0, stream>>>(off, cnt, csr2, xw2h, dinv, b2, out, N);
}